// Round 1
// baseline (2849.478 us; speedup 1.0000x reference)
//
#include <hip/hip_runtime.h>
#include <math.h>

#define N_NODES 50000
#define N_EDGES 400000
#define DIM_IN  128
#define H       128
#define E_DIM   16
#define NLAYERS 3

#define K1      272        // 2H + E_DIM
#define TE      16         // edge/node rows per block (one wave per block)

// ---------------------------------------------------------------------------
// proj: h = x @ W + b      x:[N,128] W:[128,128] b:[128] -> h:[N,128]
// one wave per 16 rows; lane t owns output cols t and t+64
// ---------------------------------------------------------------------------
__global__ __launch_bounds__(64)
void proj_kernel(const float* __restrict__ x, const float* __restrict__ W,
                 const float* __restrict__ b, float* __restrict__ h)
{
    __shared__ __align__(16) float A[TE][DIM_IN];
    const int t  = threadIdx.x;
    const int n0 = blockIdx.x * TE;

    for (int e = 0; e < TE; ++e) {
        const int n = n0 + e;
        A[e][t]      = x[(size_t)n * DIM_IN + t];
        A[e][64 + t] = x[(size_t)n * DIM_IN + 64 + t];
    }
    __syncthreads();

    float acc0[TE], acc1[TE];
#pragma unroll
    for (int e = 0; e < TE; ++e) { acc0[e] = 0.f; acc1[e] = 0.f; }

    for (int k = 0; k < DIM_IN; k += 4) {
        float w0[4], w1[4];
#pragma unroll
        for (int j = 0; j < 4; ++j) {
            w0[j] = W[(k + j) * H + t];
            w1[j] = W[(k + j) * H + 64 + t];
        }
#pragma unroll
        for (int e = 0; e < TE; ++e) {
            const float4 a = *(const float4*)&A[e][k];
            acc0[e] += a.x * w0[0] + a.y * w0[1] + a.z * w0[2] + a.w * w0[3];
            acc1[e] += a.x * w1[0] + a.y * w1[1] + a.z * w1[2] + a.w * w1[3];
        }
    }

    const float bb0 = b[t], bb1 = b[64 + t];
    for (int e = 0; e < TE; ++e) {
        const int n = n0 + e;
        h[(size_t)n * H + t]      = acc0[e] + bb0;
        h[(size_t)n * H + 64 + t] = acc1[e] + bb1;
    }
}

// ---------------------------------------------------------------------------
// edge message MLP + scatter-add:
//   m = relu(relu([h_i, h_j, e_attr] @ W1 + b1) @ W2 + b2); agg[i] += m
// one wave per 16 edges. hid tile overlaid into A[:,0:128] after GEMM1.
// ---------------------------------------------------------------------------
__global__ __launch_bounds__(64)
void edge_kernel(const float* __restrict__ h,
                 const float* __restrict__ edge_attr,
                 const int*   __restrict__ ei,       // [2, E]
                 const float* __restrict__ W1,       // [272,128]
                 const float* __restrict__ b1,       // [128]
                 const float* __restrict__ W2,       // [128,128]
                 const float* __restrict__ b2,       // [128]
                 float*       __restrict__ agg)      // [N,128]
{
    __shared__ __align__(16) float A[TE][K1];
    const int t  = threadIdx.x;
    const int e0 = blockIdx.x * TE;

    // stage [h_i | h_j | e_attr] per edge
    for (int e = 0; e < TE; ++e) {
        const int ge  = e0 + e;
        const int src = ei[ge];             // i_idx (dest of aggregation too)
        const int dst = ei[N_EDGES + ge];   // j_idx
        A[e][t]        = h[(size_t)src * H + t];
        A[e][64 + t]   = h[(size_t)src * H + 64 + t];
        A[e][128 + t]  = h[(size_t)dst * H + t];
        A[e][192 + t]  = h[(size_t)dst * H + 64 + t];
        if (t < E_DIM) A[e][256 + t] = edge_attr[(size_t)ge * E_DIM + t];
    }
    __syncthreads();

    float acc0[TE], acc1[TE];
#pragma unroll
    for (int e = 0; e < TE; ++e) { acc0[e] = 0.f; acc1[e] = 0.f; }

    // GEMM1: K = 272
    for (int k = 0; k < K1; k += 4) {
        float w0[4], w1[4];
#pragma unroll
        for (int j = 0; j < 4; ++j) {
            w0[j] = W1[(k + j) * H + t];
            w1[j] = W1[(k + j) * H + 64 + t];
        }
#pragma unroll
        for (int e = 0; e < TE; ++e) {
            const float4 a = *(const float4*)&A[e][k];
            acc0[e] += a.x * w0[0] + a.y * w0[1] + a.z * w0[2] + a.w * w0[3];
            acc1[e] += a.x * w1[0] + a.y * w1[1] + a.z * w1[2] + a.w * w1[3];
        }
    }
    __syncthreads();   // all GEMM1 reads of A complete before overwrite

    // hid = relu(acc + b1) -> overlay into A[:,0:128]
    {
        const float bb0 = b1[t], bb1 = b1[64 + t];
#pragma unroll
        for (int e = 0; e < TE; ++e) {
            A[e][t]      = fmaxf(acc0[e] + bb0, 0.f);
            A[e][64 + t] = fmaxf(acc1[e] + bb1, 0.f);
        }
    }
    __syncthreads();

#pragma unroll
    for (int e = 0; e < TE; ++e) { acc0[e] = 0.f; acc1[e] = 0.f; }

    // GEMM2: K = 128 (rows of A, stride K1)
    for (int k = 0; k < H; k += 4) {
        float w0[4], w1[4];
#pragma unroll
        for (int j = 0; j < 4; ++j) {
            w0[j] = W2[(k + j) * H + t];
            w1[j] = W2[(k + j) * H + 64 + t];
        }
#pragma unroll
        for (int e = 0; e < TE; ++e) {
            const float4 a = *(const float4*)&A[e][k];
            acc0[e] += a.x * w0[0] + a.y * w0[1] + a.z * w0[2] + a.w * w0[3];
            acc1[e] += a.x * w1[0] + a.y * w1[1] + a.z * w1[2] + a.w * w1[3];
        }
    }

    // m = relu(acc + b2); scatter-add to agg[i_idx]
    const float c0 = b2[t], c1 = b2[64 + t];
    for (int e = 0; e < TE; ++e) {
        const int ge  = e0 + e;
        const int dstn = ei[ge];   // i_idx
        atomicAdd(&agg[(size_t)dstn * H + t],      fmaxf(acc0[e] + c0, 0.f));
        atomicAdd(&agg[(size_t)dstn * H + 64 + t], fmaxf(acc1[e] + c1, 0.f));
    }
}

// ---------------------------------------------------------------------------
// node update: out = relu([h, agg] @ W + b); h = LN(out + h; g, bln)
// one wave per 16 nodes; in-place h update (rows are block-exclusive)
// ---------------------------------------------------------------------------
__global__ __launch_bounds__(64)
void update_kernel(float* __restrict__ h, const float* __restrict__ agg,
                   const float* __restrict__ W,   // [256,128]
                   const float* __restrict__ b,
                   const float* __restrict__ g, const float* __restrict__ bln)
{
    __shared__ __align__(16) float A[TE][256];
    const int t  = threadIdx.x;
    const int n0 = blockIdx.x * TE;

    for (int e = 0; e < TE; ++e) {
        const int n = n0 + e;
        A[e][t]        = h[(size_t)n * H + t];
        A[e][64 + t]   = h[(size_t)n * H + 64 + t];
        A[e][128 + t]  = agg[(size_t)n * H + t];
        A[e][192 + t]  = agg[(size_t)n * H + 64 + t];
    }
    __syncthreads();

    float acc0[TE], acc1[TE];
#pragma unroll
    for (int e = 0; e < TE; ++e) { acc0[e] = 0.f; acc1[e] = 0.f; }

    for (int k = 0; k < 256; k += 4) {
        float w0[4], w1[4];
#pragma unroll
        for (int j = 0; j < 4; ++j) {
            w0[j] = W[(k + j) * H + t];
            w1[j] = W[(k + j) * H + 64 + t];
        }
#pragma unroll
        for (int e = 0; e < TE; ++e) {
            const float4 a = *(const float4*)&A[e][k];
            acc0[e] += a.x * w0[0] + a.y * w0[1] + a.z * w0[2] + a.w * w0[3];
            acc1[e] += a.x * w1[0] + a.y * w1[1] + a.z * w1[2] + a.w * w1[3];
        }
    }

    const float bb0 = b[t],   bb1 = b[64 + t];
    const float g0  = g[t],   g1  = g[64 + t];
    const float l0  = bln[t], l1  = bln[64 + t];

    for (int e = 0; e < TE; ++e) {
        const int n = n0 + e;
        // residual: out + h  (h re-read from LDS A[:,0:128])
        float v0 = fmaxf(acc0[e] + bb0, 0.f) + A[e][t];
        float v1 = fmaxf(acc1[e] + bb1, 0.f) + A[e][64 + t];
        float s = v0 + v1;
#pragma unroll
        for (int off = 32; off > 0; off >>= 1) s += __shfl_xor(s, off, 64);
        const float mu = s * (1.f / 128.f);
        const float d0 = v0 - mu, d1 = v1 - mu;
        float vs = d0 * d0 + d1 * d1;
#pragma unroll
        for (int off = 32; off > 0; off >>= 1) vs += __shfl_xor(vs, off, 64);
        const float inv = rsqrtf(vs * (1.f / 128.f) + 1e-5f);
        h[(size_t)n * H + t]      = d0 * inv * g0 + l0;
        h[(size_t)n * H + 64 + t] = d1 * inv * g1 + l1;
    }
}

// ---------------------------------------------------------------------------
// final: out[c] = mean_n LN(h[n]; out_g, out_b)[c]
// ---------------------------------------------------------------------------
__global__ __launch_bounds__(64)
void final_kernel(const float* __restrict__ h,
                  const float* __restrict__ g, const float* __restrict__ b,
                  float* __restrict__ out)
{
    const int t = threadIdx.x;
    const float g0 = g[t], g1 = g[64 + t];
    const float b0 = b[t], b1 = b[64 + t];
    float a0 = 0.f, a1 = 0.f;

    for (int n = blockIdx.x; n < N_NODES; n += gridDim.x) {
        const float v0 = h[(size_t)n * H + t];
        const float v1 = h[(size_t)n * H + 64 + t];
        float s = v0 + v1;
#pragma unroll
        for (int off = 32; off > 0; off >>= 1) s += __shfl_xor(s, off, 64);
        const float mu = s * (1.f / 128.f);
        const float d0 = v0 - mu, d1 = v1 - mu;
        float vs = d0 * d0 + d1 * d1;
#pragma unroll
        for (int off = 32; off > 0; off >>= 1) vs += __shfl_xor(vs, off, 64);
        const float inv = rsqrtf(vs * (1.f / 128.f) + 1e-5f);
        a0 += d0 * inv * g0 + b0;
        a1 += d1 * inv * g1 + b1;
    }
    atomicAdd(&out[t],      a0 * (1.f / N_NODES));
    atomicAdd(&out[64 + t], a1 * (1.f / N_NODES));
}

// ---------------------------------------------------------------------------
extern "C" void kernel_launch(void* const* d_in, const int* in_sizes, int n_in,
                              void* d_out, int out_size, void* d_ws, size_t ws_size,
                              hipStream_t stream)
{
    const float* x         = (const float*)d_in[0];
    const float* edge_attr = (const float*)d_in[1];
    const int*   edge_idx  = (const int*)  d_in[2];
    const float* proj_W    = (const float*)d_in[3];
    const float* proj_b    = (const float*)d_in[4];
    const float* msg_W1    = (const float*)d_in[5];
    const float* msg_b1    = (const float*)d_in[6];
    const float* msg_W2    = (const float*)d_in[7];
    const float* msg_b2    = (const float*)d_in[8];
    const float* upd_W     = (const float*)d_in[9];
    const float* upd_b     = (const float*)d_in[10];
    const float* ln_g      = (const float*)d_in[11];
    const float* ln_b      = (const float*)d_in[12];
    const float* out_g     = (const float*)d_in[13];
    const float* out_b     = (const float*)d_in[14];
    float* out = (float*)d_out;

    float* h   = (float*)d_ws;                       // [N, H]
    float* agg = h + (size_t)N_NODES * H;            // [N, H]

    proj_kernel<<<N_NODES / TE, 64, 0, stream>>>(x, proj_W, proj_b, h);

    for (int l = 0; l < NLAYERS; ++l) {
        hipMemsetAsync(agg, 0, (size_t)N_NODES * H * sizeof(float), stream);
        edge_kernel<<<N_EDGES / TE, 64, 0, stream>>>(
            h, edge_attr, edge_idx,
            msg_W1 + (size_t)l * K1 * H, msg_b1 + (size_t)l * H,
            msg_W2 + (size_t)l * H * H,  msg_b2 + (size_t)l * H, agg);
        update_kernel<<<N_NODES / TE, 64, 0, stream>>>(
            h, agg, upd_W + (size_t)l * 256 * H, upd_b + (size_t)l * H,
            ln_g + (size_t)l * H, ln_b + (size_t)l * H);
    }

    hipMemsetAsync(out, 0, H * sizeof(float), stream);
    final_kernel<<<512, 64, 0, stream>>>(h, out_g, out_b, out);
}

// Round 2
// 1100.563 us; speedup vs baseline: 2.5891x; 2.5891x over previous
//
#include <hip/hip_runtime.h>
#include <math.h>

#define N_NODES 50000
#define N_EDGES 400000
#define DIM_IN  128
#define H       128
#define E_DIM   16
#define NLAYERS 3

#define K1      272        // 2H + E_DIM
#define K1P     288        // padded to multiple of 32
#define AS      296        // LDS row stride for A tile (pad: 148 dwords, conflict-free)
#define HS      136        // LDS row stride for hid tile (68 dwords, conflict-free)
#define TE      16         // rows per block in fp32 helper kernels
#define MB      32         // edges per block in MFMA edge kernel

typedef short  s16x8 __attribute__((ext_vector_type(8)));
typedef float  f32x4 __attribute__((ext_vector_type(4)));

__device__ inline unsigned short f2bf(float f) {
    union { float f; unsigned u; } v; v.f = f;
    unsigned r = v.u + 0x7FFFu + ((v.u >> 16) & 1u);
    return (unsigned short)(r >> 16);
}

// ---------------------------------------------------------------------------
// weight transpose+convert: W1 [L][272][128] f32 -> W1t [L][128][288] bf16 (pad 0)
// ---------------------------------------------------------------------------
__global__ __launch_bounds__(256)
void convert_w1(const float* __restrict__ W1, unsigned short* __restrict__ W1t)
{
    const int o = blockIdx.x * 256 + threadIdx.x;          // 3*128*288 = 110592
    const int l = o / (128 * K1P);
    const int r = o % (128 * K1P);
    const int n = r / K1P;
    const int k = r % K1P;
    const float v = (k < K1) ? W1[(size_t)l * K1 * H + (size_t)k * H + n] : 0.f;
    W1t[o] = f2bf(v);
}

// W2 [L][128][128] f32 -> W2t [L][128][128] bf16 (transposed)
__global__ __launch_bounds__(256)
void convert_w2(const float* __restrict__ W2, unsigned short* __restrict__ W2t)
{
    const int o = blockIdx.x * 256 + threadIdx.x;          // 3*128*128 = 49152
    const int l = o / (H * H);
    const int r = o % (H * H);
    const int n = r / H;
    const int k = r % H;
    W2t[o] = f2bf(W2[(size_t)l * H * H + (size_t)k * H + n]);
}

// ---------------------------------------------------------------------------
// proj: h = x @ W + b ; also emit bf16 mirror of h
// ---------------------------------------------------------------------------
__global__ __launch_bounds__(64)
void proj_kernel(const float* __restrict__ x, const float* __restrict__ W,
                 const float* __restrict__ b, float* __restrict__ h,
                 unsigned short* __restrict__ hbf)
{
    __shared__ __align__(16) float A[TE][DIM_IN];
    const int t  = threadIdx.x;
    const int n0 = blockIdx.x * TE;

    for (int e = 0; e < TE; ++e) {
        const int n = n0 + e;
        A[e][t]      = x[(size_t)n * DIM_IN + t];
        A[e][64 + t] = x[(size_t)n * DIM_IN + 64 + t];
    }
    __syncthreads();

    float acc0[TE], acc1[TE];
#pragma unroll
    for (int e = 0; e < TE; ++e) { acc0[e] = 0.f; acc1[e] = 0.f; }

    for (int k = 0; k < DIM_IN; k += 4) {
        float w0[4], w1[4];
#pragma unroll
        for (int j = 0; j < 4; ++j) {
            w0[j] = W[(k + j) * H + t];
            w1[j] = W[(k + j) * H + 64 + t];
        }
#pragma unroll
        for (int e = 0; e < TE; ++e) {
            const float4 a = *(const float4*)&A[e][k];
            acc0[e] += a.x * w0[0] + a.y * w0[1] + a.z * w0[2] + a.w * w0[3];
            acc1[e] += a.x * w1[0] + a.y * w1[1] + a.z * w1[2] + a.w * w1[3];
        }
    }

    const float bb0 = b[t], bb1 = b[64 + t];
    for (int e = 0; e < TE; ++e) {
        const int n = n0 + e;
        const float v0 = acc0[e] + bb0, v1 = acc1[e] + bb1;
        h[(size_t)n * H + t]        = v0;
        h[(size_t)n * H + 64 + t]   = v1;
        hbf[(size_t)n * H + t]      = f2bf(v0);
        hbf[(size_t)n * H + 64 + t] = f2bf(v1);
    }
}

// ---------------------------------------------------------------------------
// edge message MLP (bf16 MFMA) + fp32 atomic scatter-add
//   m = relu(relu([h_i,h_j,e]W1+b1)W2+b2);  agg[i] += m
// block: 256 thr (4 waves) x 32 edges. Wave w owns output cols [32w,32w+32).
// ---------------------------------------------------------------------------
__global__ __launch_bounds__(256)
void edge_kernel(const unsigned short* __restrict__ hbf,   // [N][128] bf16
                 const float* __restrict__ edge_attr,      // [E][16]
                 const int*   __restrict__ ei,             // [2][E]
                 const unsigned short* __restrict__ W1t,   // [128][288] bf16
                 const float* __restrict__ b1,
                 const unsigned short* __restrict__ W2t,   // [128][128] bf16
                 const float* __restrict__ b2,
                 float*       __restrict__ agg)            // [N][128]
{
    __shared__ __align__(16) unsigned short A[MB][AS];     // 18944 B
    __shared__ int idx_i[MB];
    __shared__ int idx_j[MB];
    unsigned short* Hid = &A[0][0];                        // overlaid [32][HS]

    const int tid  = threadIdx.x;
    const int e0   = blockIdx.x * MB;
    const int wave = tid >> 6;
    const int lane = tid & 63;
    const int l15  = lane & 15;
    const int l4   = lane >> 4;
    const int colbase = wave * 32;

    if (tid < MB)            idx_i[tid]      = ei[e0 + tid];
    else if (tid < 2 * MB)   idx_j[tid - MB] = ei[N_EDGES + e0 + (tid - MB)];
    __syncthreads();

    // gather h_i | h_j (uint4 = 8 bf16 chunks)
#pragma unroll
    for (int i = 0; i < 4; ++i) {
        const int f = tid + i * 256;          // 0..1023
        const int e = f >> 5;
        const int c = f & 31;
        const int node = (c < 16) ? idx_i[e] : idx_j[e];
        const int ch = c & 15;
        const uint4 v = *((const uint4*)(hbf + (size_t)node * H) + ch);
        *(uint4*)&A[e][(c < 16 ? 0 : 128) + ch * 8] = v;
    }
    // edge_attr -> bf16, plus zero pad [272..288)
    {
        const int f = tid * 2;                // 0..510 even
        const int e = f >> 4;
        const int j = f & 15;
        const float2 v = *(const float2*)&edge_attr[(size_t)(e0 + e) * E_DIM + j];
        A[e][256 + j]     = f2bf(v.x);
        A[e][256 + j + 1] = f2bf(v.y);
        A[e][272 + j]     = 0;
        A[e][272 + j + 1] = 0;
    }
    __syncthreads();

    // ---- GEMM1: [32 x 288] @ [288 x 128] -> hid
    f32x4 acc[2][2];
#pragma unroll
    for (int mt = 0; mt < 2; ++mt)
#pragma unroll
        for (int nt = 0; nt < 2; ++nt) acc[mt][nt] = (f32x4)0.f;

    for (int k = 0; k < K1P; k += 32) {
        const s16x8 a0 = *(const s16x8*)&A[l15][k + l4 * 8];
        const s16x8 a1 = *(const s16x8*)&A[16 + l15][k + l4 * 8];
        const s16x8 b0 = *(const s16x8*)&W1t[(size_t)(colbase + l15) * K1P + k + l4 * 8];
        const s16x8 bb = *(const s16x8*)&W1t[(size_t)(colbase + 16 + l15) * K1P + k + l4 * 8];
        acc[0][0] = __builtin_amdgcn_mfma_f32_16x16x32_bf16(a0, b0, acc[0][0], 0, 0, 0);
        acc[0][1] = __builtin_amdgcn_mfma_f32_16x16x32_bf16(a0, bb, acc[0][1], 0, 0, 0);
        acc[1][0] = __builtin_amdgcn_mfma_f32_16x16x32_bf16(a1, b0, acc[1][0], 0, 0, 0);
        acc[1][1] = __builtin_amdgcn_mfma_f32_16x16x32_bf16(a1, bb, acc[1][1], 0, 0, 0);
    }
    __syncthreads();   // A reads complete everywhere before overlay write

    // hid = relu(acc + b1) -> LDS bf16 (C layout: row=mt*16+l4*4+r, col=colbase+nt*16+l15)
    {
        const float bi0 = b1[colbase + l15];
        const float bi1 = b1[colbase + 16 + l15];
#pragma unroll
        for (int mt = 0; mt < 2; ++mt)
#pragma unroll
            for (int r = 0; r < 4; ++r) {
                const int row = mt * 16 + l4 * 4 + r;
                Hid[row * HS + colbase + l15]      = f2bf(fmaxf(acc[mt][0][r] + bi0, 0.f));
                Hid[row * HS + colbase + 16 + l15] = f2bf(fmaxf(acc[mt][1][r] + bi1, 0.f));
            }
    }
    __syncthreads();

    // ---- GEMM2: [32 x 128] @ [128 x 128] -> m
#pragma unroll
    for (int mt = 0; mt < 2; ++mt)
#pragma unroll
        for (int nt = 0; nt < 2; ++nt) acc[mt][nt] = (f32x4)0.f;

    for (int k = 0; k < H; k += 32) {
        const s16x8 a0 = *(const s16x8*)&Hid[l15 * HS + k + l4 * 8];
        const s16x8 a1 = *(const s16x8*)&Hid[(16 + l15) * HS + k + l4 * 8];
        const s16x8 b0 = *(const s16x8*)&W2t[(size_t)(colbase + l15) * H + k + l4 * 8];
        const s16x8 bb = *(const s16x8*)&W2t[(size_t)(colbase + 16 + l15) * H + k + l4 * 8];
        acc[0][0] = __builtin_amdgcn_mfma_f32_16x16x32_bf16(a0, b0, acc[0][0], 0, 0, 0);
        acc[0][1] = __builtin_amdgcn_mfma_f32_16x16x32_bf16(a0, bb, acc[0][1], 0, 0, 0);
        acc[1][0] = __builtin_amdgcn_mfma_f32_16x16x32_bf16(a1, b0, acc[1][0], 0, 0, 0);
        acc[1][1] = __builtin_amdgcn_mfma_f32_16x16x32_bf16(a1, bb, acc[1][1], 0, 0, 0);
    }

    // m = relu(acc + b2); scatter
    {
        const float bi0 = b2[colbase + l15];
        const float bi1 = b2[colbase + 16 + l15];
#pragma unroll
        for (int mt = 0; mt < 2; ++mt)
#pragma unroll
            for (int r = 0; r < 4; ++r) {
                const int row  = mt * 16 + l4 * 4 + r;
                const int node = idx_i[row];
                float* dst = agg + (size_t)node * H;
                atomicAdd(dst + colbase + l15,      fmaxf(acc[mt][0][r] + bi0, 0.f));
                atomicAdd(dst + colbase + 16 + l15, fmaxf(acc[mt][1][r] + bi1, 0.f));
            }
    }
}

// ---------------------------------------------------------------------------
// node update: out = relu([h,agg]W+b); h = LN(out+h); also bf16 mirror
// ---------------------------------------------------------------------------
__global__ __launch_bounds__(64)
void update_kernel(float* __restrict__ h, const float* __restrict__ agg,
                   const float* __restrict__ W, const float* __restrict__ b,
                   const float* __restrict__ g, const float* __restrict__ bln,
                   unsigned short* __restrict__ hbf)
{
    __shared__ __align__(16) float A[TE][256];
    const int t  = threadIdx.x;
    const int n0 = blockIdx.x * TE;

    for (int e = 0; e < TE; ++e) {
        const int n = n0 + e;
        A[e][t]        = h[(size_t)n * H + t];
        A[e][64 + t]   = h[(size_t)n * H + 64 + t];
        A[e][128 + t]  = agg[(size_t)n * H + t];
        A[e][192 + t]  = agg[(size_t)n * H + 64 + t];
    }
    __syncthreads();

    float acc0[TE], acc1[TE];
#pragma unroll
    for (int e = 0; e < TE; ++e) { acc0[e] = 0.f; acc1[e] = 0.f; }

    for (int k = 0; k < 256; k += 4) {
        float w0[4], w1[4];
#pragma unroll
        for (int j = 0; j < 4; ++j) {
            w0[j] = W[(k + j) * H + t];
            w1[j] = W[(k + j) * H + 64 + t];
        }
#pragma unroll
        for (int e = 0; e < TE; ++e) {
            const float4 a = *(const float4*)&A[e][k];
            acc0[e] += a.x * w0[0] + a.y * w0[1] + a.z * w0[2] + a.w * w0[3];
            acc1[e] += a.x * w1[0] + a.y * w1[1] + a.z * w1[2] + a.w * w1[3];
        }
    }

    const float bb0 = b[t],   bb1 = b[64 + t];
    const float g0  = g[t],   g1  = g[64 + t];
    const float l0  = bln[t], l1  = bln[64 + t];

    for (int e = 0; e < TE; ++e) {
        const int n = n0 + e;
        float v0 = fmaxf(acc0[e] + bb0, 0.f) + A[e][t];
        float v1 = fmaxf(acc1[e] + bb1, 0.f) + A[e][64 + t];
        float s = v0 + v1;
#pragma unroll
        for (int off = 32; off > 0; off >>= 1) s += __shfl_xor(s, off, 64);
        const float mu = s * (1.f / 128.f);
        const float d0 = v0 - mu, d1 = v1 - mu;
        float vs = d0 * d0 + d1 * d1;
#pragma unroll
        for (int off = 32; off > 0; off >>= 1) vs += __shfl_xor(vs, off, 64);
        const float inv = rsqrtf(vs * (1.f / 128.f) + 1e-5f);
        const float o0 = d0 * inv * g0 + l0;
        const float o1 = d1 * inv * g1 + l1;
        h[(size_t)n * H + t]        = o0;
        h[(size_t)n * H + 64 + t]   = o1;
        hbf[(size_t)n * H + t]      = f2bf(o0);
        hbf[(size_t)n * H + 64 + t] = f2bf(o1);
    }
}

// ---------------------------------------------------------------------------
__global__ __launch_bounds__(64)
void final_kernel(const float* __restrict__ h,
                  const float* __restrict__ g, const float* __restrict__ b,
                  float* __restrict__ out)
{
    const int t = threadIdx.x;
    const float g0 = g[t], g1 = g[64 + t];
    const float b0 = b[t], b1 = b[64 + t];
    float a0 = 0.f, a1 = 0.f;

    for (int n = blockIdx.x; n < N_NODES; n += gridDim.x) {
        const float v0 = h[(size_t)n * H + t];
        const float v1 = h[(size_t)n * H + 64 + t];
        float s = v0 + v1;
#pragma unroll
        for (int off = 32; off > 0; off >>= 1) s += __shfl_xor(s, off, 64);
        const float mu = s * (1.f / 128.f);
        const float d0 = v0 - mu, d1 = v1 - mu;
        float vs = d0 * d0 + d1 * d1;
#pragma unroll
        for (int off = 32; off > 0; off >>= 1) vs += __shfl_xor(vs, off, 64);
        const float inv = rsqrtf(vs * (1.f / 128.f) + 1e-5f);
        a0 += d0 * inv * g0 + b0;
        a1 += d1 * inv * g1 + b1;
    }
    atomicAdd(&out[t],      a0 * (1.f / N_NODES));
    atomicAdd(&out[64 + t], a1 * (1.f / N_NODES));
}

// ---------------------------------------------------------------------------
extern "C" void kernel_launch(void* const* d_in, const int* in_sizes, int n_in,
                              void* d_out, int out_size, void* d_ws, size_t ws_size,
                              hipStream_t stream)
{
    const float* x         = (const float*)d_in[0];
    const float* edge_attr = (const float*)d_in[1];
    const int*   edge_idx  = (const int*)  d_in[2];
    const float* proj_W    = (const float*)d_in[3];
    const float* proj_b    = (const float*)d_in[4];
    const float* msg_W1    = (const float*)d_in[5];
    const float* msg_b1    = (const float*)d_in[6];
    const float* msg_W2    = (const float*)d_in[7];
    const float* msg_b2    = (const float*)d_in[8];
    const float* upd_W     = (const float*)d_in[9];
    const float* upd_b     = (const float*)d_in[10];
    const float* ln_g      = (const float*)d_in[11];
    const float* ln_b      = (const float*)d_in[12];
    const float* out_g     = (const float*)d_in[13];
    const float* out_b     = (const float*)d_in[14];
    float* out = (float*)d_out;

    // workspace layout
    float* h   = (float*)d_ws;                               // 25.6 MB
    float* agg = h + (size_t)N_NODES * H;                    // 25.6 MB
    unsigned short* hbf = (unsigned short*)(agg + (size_t)N_NODES * H);   // 12.8 MB
    unsigned short* W1t = hbf + (size_t)N_NODES * H;         // 3*128*288 bf16
    unsigned short* W2t = W1t + (size_t)NLAYERS * H * K1P;   // 3*128*128 bf16

    convert_w1<<<(NLAYERS * H * K1P) / 256, 256, 0, stream>>>(msg_W1, W1t);
    convert_w2<<<(NLAYERS * H * H) / 256, 256, 0, stream>>>(msg_W2, W2t);

    proj_kernel<<<N_NODES / TE, 64, 0, stream>>>(x, proj_W, proj_b, h, hbf);

    for (int l = 0; l < NLAYERS; ++l) {
        hipMemsetAsync(agg, 0, (size_t)N_NODES * H * sizeof(float), stream);
        edge_kernel<<<N_EDGES / MB, 256, 0, stream>>>(
            hbf, edge_attr, edge_idx,
            W1t + (size_t)l * H * K1P, msg_b1 + (size_t)l * H,
            W2t + (size_t)l * H * H,   msg_b2 + (size_t)l * H, agg);
        update_kernel<<<N_NODES / TE, 64, 0, stream>>>(
            h, agg, upd_W + (size_t)l * 256 * H, upd_b + (size_t)l * H,
            ln_g + (size_t)l * H, ln_b + (size_t)l * H, hbf);
    }

    hipMemsetAsync(out, 0, H * sizeof(float), stream);
    final_kernel<<<512, 64, 0, stream>>>(h, out_g, out_b, out);
}

// Round 3
// 810.935 us; speedup vs baseline: 3.5138x; 1.3572x over previous
//
#include <hip/hip_runtime.h>
#include <math.h>

#define N_NODES 50000
#define N_EDGES 400000
#define DIM_IN  128
#define H       128
#define E_DIM   16
#define NLAYERS 3

#define K1      272        // 2H + E_DIM
#define K1P     288        // padded to multiple of 32
#define AS      296        // edge A-tile row stride (shorts)
#define HS      136        // hid tile row stride (shorts)
#define US      264        // update A-tile row stride (shorts): 256 + 8 pad
#define PS      136        // proj A-tile row stride (shorts)
#define FPS     132        // fp32 overlay row stride (floats)
#define MB      32         // rows (edges/nodes) per MFMA block

typedef short  s16x8 __attribute__((ext_vector_type(8)));
typedef float  f32x4 __attribute__((ext_vector_type(4)));

__device__ inline unsigned short f2bf(float f) {
    union { float f; unsigned u; } v; v.f = f;
    unsigned r = v.u + 0x7FFFu + ((v.u >> 16) & 1u);
    return (unsigned short)(r >> 16);
}

// ---------------------------------------------------------------------------
// weight convert/transpose kernels (tiny, once per launch)
// ---------------------------------------------------------------------------
__global__ __launch_bounds__(256)
void convert_w1(const float* __restrict__ W1, unsigned short* __restrict__ W1t)
{   // [L][272][128] f32 -> [L][128][288] bf16 (zero pad)
    const int o = blockIdx.x * 256 + threadIdx.x;
    const int l = o / (128 * K1P);
    const int r = o % (128 * K1P);
    const int n = r / K1P;
    const int k = r % K1P;
    const float v = (k < K1) ? W1[(size_t)l * K1 * H + (size_t)k * H + n] : 0.f;
    W1t[o] = f2bf(v);
}

__global__ __launch_bounds__(256)
void convert_w2(const float* __restrict__ W2, unsigned short* __restrict__ W2t)
{   // [L][128][128] -> transposed bf16
    const int o = blockIdx.x * 256 + threadIdx.x;
    const int l = o / (H * H);
    const int r = o % (H * H);
    const int n = r / H;
    const int k = r % H;
    W2t[o] = f2bf(W2[(size_t)l * H * H + (size_t)k * H + n]);
}

__global__ __launch_bounds__(256)
void convert_wu(const float* __restrict__ Wu, unsigned short* __restrict__ Wut)
{   // [L][256][128] -> [L][128][256] bf16
    const int o = blockIdx.x * 256 + threadIdx.x;
    const int l = o / (H * 256);
    const int r = o % (H * 256);
    const int n = r / 256;
    const int k = r % 256;
    Wut[o] = f2bf(Wu[(size_t)l * 256 * H + (size_t)k * H + n]);
}

__global__ __launch_bounds__(256)
void convert_wp(const float* __restrict__ Wp, unsigned short* __restrict__ Wpt)
{   // [128][128] -> transposed bf16
    const int o = blockIdx.x * 256 + threadIdx.x;
    const int n = o / H;
    const int k = o % H;
    Wpt[o] = f2bf(Wp[(size_t)k * H + n]);
}

// ---------------------------------------------------------------------------
// counting sort of edges by destination (i_idx)
// ---------------------------------------------------------------------------
__global__ __launch_bounds__(256)
void hist_kernel(const int* __restrict__ ei, int* __restrict__ hist)
{
    const int e = blockIdx.x * 256 + threadIdx.x;
    if (e < N_EDGES) atomicAdd(&hist[ei[e]], 1);
}

__global__ __launch_bounds__(256)
void scan_kernel(const int* __restrict__ hist, int* __restrict__ cursor)
{
    __shared__ int ps[256];
    const int t = threadIdx.x;
    const int CH = 196;                     // 256*196 = 50176 >= N
    const int base = t * CH;
    int s = 0;
    for (int i = 0; i < CH; ++i) { const int idx = base + i; if (idx < N_NODES) s += hist[idx]; }
    ps[t] = s; __syncthreads();
    for (int off = 1; off < 256; off <<= 1) {
        const int v = (t >= off) ? ps[t - off] : 0;
        __syncthreads();
        ps[t] += v;
        __syncthreads();
    }
    int run = (t > 0) ? ps[t - 1] : 0;
    for (int i = 0; i < CH; ++i) {
        const int idx = base + i;
        if (idx < N_NODES) { cursor[idx] = run; run += hist[idx]; }
    }
}

__global__ __launch_bounds__(256)
void scatter_kernel(const int* __restrict__ ei, int* __restrict__ cursor,
                    int* __restrict__ i_s, int* __restrict__ j_s, int* __restrict__ perm)
{
    const int e = blockIdx.x * 256 + threadIdx.x;
    if (e < N_EDGES) {
        const int d = ei[e];
        const int p = atomicAdd(&cursor[d], 1);
        i_s[p] = d;
        j_s[p] = ei[N_EDGES + e];
        perm[p] = e;
    }
}

// ---------------------------------------------------------------------------
// proj (MFMA): h = x @ Wp + b; emit fp32 h and bf16 mirror
// ---------------------------------------------------------------------------
__global__ __launch_bounds__(256)
void proj_mfma(const float* __restrict__ x, const unsigned short* __restrict__ Wpt,
               const float* __restrict__ b, float* __restrict__ h,
               unsigned short* __restrict__ hbf)
{
    __shared__ __align__(16) unsigned short A[MB][PS];
    const int tid = threadIdx.x;
    const int n0 = blockIdx.x * MB;
    const int wave = tid >> 6, lane = tid & 63, l15 = lane & 15, l4 = lane >> 4;
    const int colbase = wave * 32;

#pragma unroll
    for (int i = 0; i < 4; ++i) {
        const int f = tid + i * 256;        // 0..1023 float4 chunks
        const int row = f >> 5, c4 = f & 31;
        const int node = min(n0 + row, N_NODES - 1);
        const float4 v = *((const float4*)(x + (size_t)node * DIM_IN) + c4);
        unsigned short o[4] = { f2bf(v.x), f2bf(v.y), f2bf(v.z), f2bf(v.w) };
        *(uint2*)&A[row][c4 * 4] = *(const uint2*)o;
    }
    __syncthreads();

    f32x4 acc[2][2];
#pragma unroll
    for (int mt = 0; mt < 2; ++mt)
#pragma unroll
        for (int nt = 0; nt < 2; ++nt) acc[mt][nt] = (f32x4)0.f;

    for (int k = 0; k < DIM_IN; k += 32) {
        const s16x8 a0 = *(const s16x8*)&A[l15][k + l4 * 8];
        const s16x8 a1 = *(const s16x8*)&A[16 + l15][k + l4 * 8];
        const s16x8 b0 = *(const s16x8*)&Wpt[(size_t)(colbase + l15) * DIM_IN + k + l4 * 8];
        const s16x8 b1 = *(const s16x8*)&Wpt[(size_t)(colbase + 16 + l15) * DIM_IN + k + l4 * 8];
        acc[0][0] = __builtin_amdgcn_mfma_f32_16x16x32_bf16(a0, b0, acc[0][0], 0, 0, 0);
        acc[0][1] = __builtin_amdgcn_mfma_f32_16x16x32_bf16(a0, b1, acc[0][1], 0, 0, 0);
        acc[1][0] = __builtin_amdgcn_mfma_f32_16x16x32_bf16(a1, b0, acc[1][0], 0, 0, 0);
        acc[1][1] = __builtin_amdgcn_mfma_f32_16x16x32_bf16(a1, b1, acc[1][1], 0, 0, 0);
    }

    const float bi0 = b[colbase + l15], bi1 = b[colbase + 16 + l15];
#pragma unroll
    for (int mt = 0; mt < 2; ++mt)
#pragma unroll
        for (int r = 0; r < 4; ++r) {
            const int row = mt * 16 + l4 * 4 + r;
            const int n = n0 + row;
            if (n < N_NODES) {
                const float v0 = acc[mt][0][r] + bi0;
                const float v1 = acc[mt][1][r] + bi1;
                h[(size_t)n * H + colbase + l15]        = v0;
                h[(size_t)n * H + colbase + 16 + l15]   = v1;
                hbf[(size_t)n * H + colbase + l15]      = f2bf(v0);
                hbf[(size_t)n * H + colbase + 16 + l15] = f2bf(v1);
            }
        }
}

// ---------------------------------------------------------------------------
// edge message MLP (bf16 MFMA) on dest-sorted edges + LDS segment-reduce
// ---------------------------------------------------------------------------
__global__ __launch_bounds__(256)
void edge_kernel(const unsigned short* __restrict__ hbf,
                 const float* __restrict__ edge_attr,
                 const int*   __restrict__ i_s,      // sorted dest
                 const int*   __restrict__ j_s,      // sorted src
                 const int*   __restrict__ perm,     // sorted -> original edge id
                 const unsigned short* __restrict__ W1t,
                 const float* __restrict__ b1,
                 const unsigned short* __restrict__ W2t,
                 const float* __restrict__ b2,
                 float*       __restrict__ agg)
{
    __shared__ __align__(16) unsigned short A[MB][AS];   // 18944 B
    __shared__ int idx_i[MB];
    __shared__ int idx_j[MB];
    __shared__ int perm_s[MB];
    unsigned short* Hid = &A[0][0];                      // [32][HS] overlay
    float* Afp = (float*)&A[0][0];                       // [32][FPS] overlay

    const int tid  = threadIdx.x;
    const int e0   = blockIdx.x * MB;
    const int wave = tid >> 6;
    const int lane = tid & 63;
    const int l15  = lane & 15;
    const int l4   = lane >> 4;
    const int colbase = wave * 32;

    if (tid < MB)            idx_i[tid]           = i_s[e0 + tid];
    else if (tid < 2 * MB)   idx_j[tid - MB]      = j_s[e0 + (tid - MB)];
    else if (tid < 3 * MB)   perm_s[tid - 2 * MB] = perm[e0 + (tid - 2 * MB)];
    __syncthreads();

    // gather h_i | h_j
#pragma unroll
    for (int i = 0; i < 4; ++i) {
        const int f = tid + i * 256;
        const int e = f >> 5;
        const int c = f & 31;
        const int node = (c < 16) ? idx_i[e] : idx_j[e];
        const int ch = c & 15;
        const uint4 v = *((const uint4*)(hbf + (size_t)node * H) + ch);
        *(uint4*)&A[e][(c < 16 ? 0 : 128) + ch * 8] = v;
    }
    // edge_attr (via perm) -> bf16 + zero pad
    {
        const int f = tid * 2;
        const int e = f >> 4;
        const int j = f & 15;
        const int pe = perm_s[e];
        const float2 v = *(const float2*)&edge_attr[(size_t)pe * E_DIM + j];
        A[e][256 + j]     = f2bf(v.x);
        A[e][256 + j + 1] = f2bf(v.y);
        A[e][272 + j]     = 0;
        A[e][272 + j + 1] = 0;
    }
    __syncthreads();

    // ---- GEMM1
    f32x4 acc[2][2];
#pragma unroll
    for (int mt = 0; mt < 2; ++mt)
#pragma unroll
        for (int nt = 0; nt < 2; ++nt) acc[mt][nt] = (f32x4)0.f;

    for (int k = 0; k < K1P; k += 32) {
        const s16x8 a0 = *(const s16x8*)&A[l15][k + l4 * 8];
        const s16x8 a1 = *(const s16x8*)&A[16 + l15][k + l4 * 8];
        const s16x8 b0 = *(const s16x8*)&W1t[(size_t)(colbase + l15) * K1P + k + l4 * 8];
        const s16x8 bb = *(const s16x8*)&W1t[(size_t)(colbase + 16 + l15) * K1P + k + l4 * 8];
        acc[0][0] = __builtin_amdgcn_mfma_f32_16x16x32_bf16(a0, b0, acc[0][0], 0, 0, 0);
        acc[0][1] = __builtin_amdgcn_mfma_f32_16x16x32_bf16(a0, bb, acc[0][1], 0, 0, 0);
        acc[1][0] = __builtin_amdgcn_mfma_f32_16x16x32_bf16(a1, b0, acc[1][0], 0, 0, 0);
        acc[1][1] = __builtin_amdgcn_mfma_f32_16x16x32_bf16(a1, bb, acc[1][1], 0, 0, 0);
    }
    __syncthreads();

    // hid = relu(acc+b1) -> LDS bf16
    {
        const float bi0 = b1[colbase + l15];
        const float bi1 = b1[colbase + 16 + l15];
#pragma unroll
        for (int mt = 0; mt < 2; ++mt)
#pragma unroll
            for (int r = 0; r < 4; ++r) {
                const int row = mt * 16 + l4 * 4 + r;
                Hid[row * HS + colbase + l15]      = f2bf(fmaxf(acc[mt][0][r] + bi0, 0.f));
                Hid[row * HS + colbase + 16 + l15] = f2bf(fmaxf(acc[mt][1][r] + bi1, 0.f));
            }
    }
    __syncthreads();

    // ---- GEMM2
#pragma unroll
    for (int mt = 0; mt < 2; ++mt)
#pragma unroll
        for (int nt = 0; nt < 2; ++nt) acc[mt][nt] = (f32x4)0.f;

    for (int k = 0; k < H; k += 32) {
        const s16x8 a0 = *(const s16x8*)&Hid[l15 * HS + k + l4 * 8];
        const s16x8 a1 = *(const s16x8*)&Hid[(16 + l15) * HS + k + l4 * 8];
        const s16x8 b0 = *(const s16x8*)&W2t[(size_t)(colbase + l15) * H + k + l4 * 8];
        const s16x8 bb = *(const s16x8*)&W2t[(size_t)(colbase + 16 + l15) * H + k + l4 * 8];
        acc[0][0] = __builtin_amdgcn_mfma_f32_16x16x32_bf16(a0, b0, acc[0][0], 0, 0, 0);
        acc[0][1] = __builtin_amdgcn_mfma_f32_16x16x32_bf16(a0, bb, acc[0][1], 0, 0, 0);
        acc[1][0] = __builtin_amdgcn_mfma_f32_16x16x32_bf16(a1, b0, acc[1][0], 0, 0, 0);
        acc[1][1] = __builtin_amdgcn_mfma_f32_16x16x32_bf16(a1, bb, acc[1][1], 0, 0, 0);
    }
    __syncthreads();   // Hid reads complete before fp32 overlay

    // m = relu(acc+b2) -> LDS fp32
    {
        const float bi0 = b2[colbase + l15];
        const float bi1 = b2[colbase + 16 + l15];
#pragma unroll
        for (int mt = 0; mt < 2; ++mt)
#pragma unroll
            for (int r = 0; r < 4; ++r) {
                const int row = mt * 16 + l4 * 4 + r;
                Afp[row * FPS + colbase + l15]      = fmaxf(acc[mt][0][r] + bi0, 0.f);
                Afp[row * FPS + colbase + 16 + l15] = fmaxf(acc[mt][1][r] + bi1, 0.f);
            }
    }
    __syncthreads();

    // segmented reduce over sorted dests: ~1 atomic per segment per column
    {
        const int c    = tid & 127;
        const int half = tid >> 7;              // rows 0..15 or 16..31
        int cur = idx_i[half * 16];
        float s = 0.f;
        for (int r = half * 16; r < half * 16 + 16; ++r) {
            const int d = idx_i[r];
            if (d != cur) {
                atomicAdd(&agg[(size_t)cur * H + c], s);
                s = 0.f; cur = d;
            }
            s += Afp[r * FPS + c];
        }
        atomicAdd(&agg[(size_t)cur * H + c], s);
    }
}

// ---------------------------------------------------------------------------
// node update (MFMA): out = relu([h,agg]Wu+b); h = LN(out+h); bf16 mirror
// ---------------------------------------------------------------------------
__global__ __launch_bounds__(256)
void update_mfma(float* __restrict__ h, const float* __restrict__ agg,
                 const unsigned short* __restrict__ Wut, const float* __restrict__ b,
                 const float* __restrict__ g, const float* __restrict__ bln,
                 unsigned short* __restrict__ hbf)
{
    __shared__ __align__(16) unsigned short A[MB][US];   // 16896 B
    float* Afp = (float*)&A[0][0];                       // [32][FPS] overlay

    const int tid = threadIdx.x;
    const int n0 = blockIdx.x * MB;
    const int wave = tid >> 6, lane = tid & 63, l15 = lane & 15, l4 = lane >> 4;
    const int colbase = wave * 32;

    // stage h (bf16 direct)
#pragma unroll
    for (int i = 0; i < 2; ++i) {
        const int f = tid + i * 256;        // 0..511 uint4 chunks
        const int row = f >> 4, c = f & 15;
        const int node = min(n0 + row, N_NODES - 1);
        const uint4 v = *((const uint4*)(hbf + (size_t)node * H) + c);
        *(uint4*)&A[row][c * 8] = v;
    }
    // stage agg (fp32 -> bf16)
#pragma unroll
    for (int i = 0; i < 4; ++i) {
        const int f = tid + i * 256;        // 0..1023 float4 chunks
        const int row = f >> 5, c4 = f & 31;
        const int node = min(n0 + row, N_NODES - 1);
        const float4 v = *((const float4*)(agg + (size_t)node * H) + c4);
        unsigned short o[4] = { f2bf(v.x), f2bf(v.y), f2bf(v.z), f2bf(v.w) };
        *(uint2*)&A[row][128 + c4 * 4] = *(const uint2*)o;
    }
    __syncthreads();

    f32x4 acc[2][2];
#pragma unroll
    for (int mt = 0; mt < 2; ++mt)
#pragma unroll
        for (int nt = 0; nt < 2; ++nt) acc[mt][nt] = (f32x4)0.f;

    for (int k = 0; k < 256; k += 32) {
        const s16x8 a0 = *(const s16x8*)&A[l15][k + l4 * 8];
        const s16x8 a1 = *(const s16x8*)&A[16 + l15][k + l4 * 8];
        const s16x8 b0 = *(const s16x8*)&Wut[(size_t)(colbase + l15) * 256 + k + l4 * 8];
        const s16x8 b1 = *(const s16x8*)&Wut[(size_t)(colbase + 16 + l15) * 256 + k + l4 * 8];
        acc[0][0] = __builtin_amdgcn_mfma_f32_16x16x32_bf16(a0, b0, acc[0][0], 0, 0, 0);
        acc[0][1] = __builtin_amdgcn_mfma_f32_16x16x32_bf16(a0, b1, acc[0][1], 0, 0, 0);
        acc[1][0] = __builtin_amdgcn_mfma_f32_16x16x32_bf16(a1, b0, acc[1][0], 0, 0, 0);
        acc[1][1] = __builtin_amdgcn_mfma_f32_16x16x32_bf16(a1, b1, acc[1][1], 0, 0, 0);
    }
    __syncthreads();   // A reads done before fp32 overlay

    // relu(acc + b) -> LDS fp32
    {
        const float bi0 = b[colbase + l15], bi1 = b[colbase + 16 + l15];
#pragma unroll
        for (int mt = 0; mt < 2; ++mt)
#pragma unroll
            for (int r = 0; r < 4; ++r) {
                const int row = mt * 16 + l4 * 4 + r;
                Afp[row * FPS + colbase + l15]      = fmaxf(acc[mt][0][r] + bi0, 0.f);
                Afp[row * FPS + colbase + 16 + l15] = fmaxf(acc[mt][1][r] + bi1, 0.f);
            }
    }
    __syncthreads();

    // LN phase: wave handles 8 rows
    const float g0 = g[lane],   g1 = g[64 + lane];
    const float l0 = bln[lane], l1 = bln[64 + lane];
    for (int q = 0; q < 8; ++q) {
        const int row = wave * 8 + q;
        const int n = n0 + row;
        if (n >= N_NODES) break;
        const float hr0 = h[(size_t)n * H + lane];
        const float hr1 = h[(size_t)n * H + 64 + lane];
        float v0 = Afp[row * FPS + lane]      + hr0;
        float v1 = Afp[row * FPS + 64 + lane] + hr1;
        float s = v0 + v1;
#pragma unroll
        for (int off = 32; off > 0; off >>= 1) s += __shfl_xor(s, off, 64);
        const float mu = s * (1.f / 128.f);
        const float d0 = v0 - mu, d1 = v1 - mu;
        float vs = d0 * d0 + d1 * d1;
#pragma unroll
        for (int off = 32; off > 0; off >>= 1) vs += __shfl_xor(vs, off, 64);
        const float inv = rsqrtf(vs * (1.f / 128.f) + 1e-5f);
        const float o0 = d0 * inv * g0 + l0;
        const float o1 = d1 * inv * g1 + l1;
        h[(size_t)n * H + lane]        = o0;
        h[(size_t)n * H + 64 + lane]   = o1;
        hbf[(size_t)n * H + lane]      = f2bf(o0);
        hbf[(size_t)n * H + 64 + lane] = f2bf(o1);
    }
}

// ---------------------------------------------------------------------------
__global__ __launch_bounds__(64)
void final_kernel(const float* __restrict__ h,
                  const float* __restrict__ g, const float* __restrict__ b,
                  float* __restrict__ out)
{
    const int t = threadIdx.x;
    const float g0 = g[t], g1 = g[64 + t];
    const float b0 = b[t], b1 = b[64 + t];
    float a0 = 0.f, a1 = 0.f;

    for (int n = blockIdx.x; n < N_NODES; n += gridDim.x) {
        const float v0 = h[(size_t)n * H + t];
        const float v1 = h[(size_t)n * H + 64 + t];
        float s = v0 + v1;
#pragma unroll
        for (int off = 32; off > 0; off >>= 1) s += __shfl_xor(s, off, 64);
        const float mu = s * (1.f / 128.f);
        const float d0 = v0 - mu, d1 = v1 - mu;
        float vs = d0 * d0 + d1 * d1;
#pragma unroll
        for (int off = 32; off > 0; off >>= 1) vs += __shfl_xor(vs, off, 64);
        const float inv = rsqrtf(vs * (1.f / 128.f) + 1e-5f);
        a0 += d0 * inv * g0 + b0;
        a1 += d1 * inv * g1 + b1;
    }
    atomicAdd(&out[t],      a0 * (1.f / N_NODES));
    atomicAdd(&out[64 + t], a1 * (1.f / N_NODES));
}

// ---------------------------------------------------------------------------
extern "C" void kernel_launch(void* const* d_in, const int* in_sizes, int n_in,
                              void* d_out, int out_size, void* d_ws, size_t ws_size,
                              hipStream_t stream)
{
    const float* x         = (const float*)d_in[0];
    const float* edge_attr = (const float*)d_in[1];
    const int*   edge_idx  = (const int*)  d_in[2];
    const float* proj_W    = (const float*)d_in[3];
    const float* proj_b    = (const float*)d_in[4];
    const float* msg_W1    = (const float*)d_in[5];
    const float* msg_b1    = (const float*)d_in[6];
    const float* msg_W2    = (const float*)d_in[7];
    const float* msg_b2    = (const float*)d_in[8];
    const float* upd_W     = (const float*)d_in[9];
    const float* upd_b     = (const float*)d_in[10];
    const float* ln_g      = (const float*)d_in[11];
    const float* ln_b      = (const float*)d_in[12];
    const float* out_g     = (const float*)d_in[13];
    const float* out_b     = (const float*)d_in[14];
    float* out = (float*)d_out;

    // workspace layout (all 16B-aligned sizes)
    char* w = (char*)d_ws;
    float* h   = (float*)w;                 w += (size_t)N_NODES * H * 4;      // 25.6 MB
    float* agg = (float*)w;                 w += (size_t)N_NODES * H * 4;      // 25.6 MB
    unsigned short* hbf = (unsigned short*)w; w += (size_t)N_NODES * H * 2;    // 12.8 MB
    unsigned short* W1t = (unsigned short*)w; w += (size_t)NLAYERS * H * K1P * 2;
    unsigned short* W2t = (unsigned short*)w; w += (size_t)NLAYERS * H * H * 2;
    unsigned short* Wut = (unsigned short*)w; w += (size_t)NLAYERS * H * 256 * 2;
    unsigned short* Wpt = (unsigned short*)w; w += (size_t)H * DIM_IN * 2;
    int* hist   = (int*)w;                  w += (size_t)N_NODES * 4;
    int* cursor = (int*)w;                  w += (size_t)N_NODES * 4;
    int* i_s    = (int*)w;                  w += (size_t)N_EDGES * 4;
    int* j_s    = (int*)w;                  w += (size_t)N_EDGES * 4;
    int* perm   = (int*)w;                  w += (size_t)N_EDGES * 4;

    // weight conversions
    convert_w1<<<(NLAYERS * H * K1P) / 256, 256, 0, stream>>>(msg_W1, W1t);
    convert_w2<<<(NLAYERS * H * H) / 256, 256, 0, stream>>>(msg_W2, W2t);
    convert_wu<<<(NLAYERS * H * 256) / 256, 256, 0, stream>>>(upd_W, Wut);
    convert_wp<<<(H * DIM_IN) / 256, 256, 0, stream>>>(proj_W, Wpt);

    // counting sort by destination
    hipMemsetAsync(hist, 0, (size_t)N_NODES * 4, stream);
    hist_kernel<<<(N_EDGES + 255) / 256, 256, 0, stream>>>(edge_idx, hist);
    scan_kernel<<<1, 256, 0, stream>>>(hist, cursor);
    scatter_kernel<<<(N_EDGES + 255) / 256, 256, 0, stream>>>(edge_idx, cursor, i_s, j_s, perm);

    const int nblk = (N_NODES + MB - 1) / MB;
    proj_mfma<<<nblk, 256, 0, stream>>>(x, Wpt, proj_b, h, hbf);

    for (int l = 0; l < NLAYERS; ++l) {
        hipMemsetAsync(agg, 0, (size_t)N_NODES * H * sizeof(float), stream);
        edge_kernel<<<N_EDGES / MB, 256, 0, stream>>>(
            hbf, edge_attr, i_s, j_s, perm,
            W1t + (size_t)l * H * K1P, msg_b1 + (size_t)l * H,
            W2t + (size_t)l * H * H,   msg_b2 + (size_t)l * H, agg);
        update_mfma<<<nblk, 256, 0, stream>>>(
            h, agg, Wut + (size_t)l * H * 256, upd_b + (size_t)l * H,
            ln_g + (size_t)l * H, ln_b + (size_t)l * H, hbf);
    }

    hipMemsetAsync(out, 0, H * sizeof(float), stream);
    final_kernel<<<512, 64, 0, stream>>>(h, out_g, out_b, out);
}

// Round 4
// 794.698 us; speedup vs baseline: 3.5856x; 1.0204x over previous
//
#include <hip/hip_runtime.h>
#include <math.h>

#define N_NODES 50000
#define N_EDGES 400000
#define DIM_IN  128
#define H       128
#define E_DIM   16
#define NLAYERS 3

#define K1      272        // 2H + E_DIM
#define K1P     288        // padded to multiple of 32
#define AS      296        // edge A-tile row stride (shorts): 592 B = 37*16 ok
#define HS      136        // hid tile row stride (shorts)
#define US      264        // update A-tile row stride (shorts)
#define PS      136        // proj A-tile row stride (shorts)
#define FPS     132        // fp32 overlay row stride (floats)
#define MB      32         // rows per MFMA tile

typedef short  s16x8 __attribute__((ext_vector_type(8)));
typedef float  f32x4 __attribute__((ext_vector_type(4)));

__device__ inline unsigned short f2bf(float f) {
    union { float f; unsigned u; } v; v.f = f;
    unsigned r = v.u + 0x7FFFu + ((v.u >> 16) & 1u);
    return (unsigned short)(r >> 16);
}

// ---------------------------------------------------------------------------
// weight convert/transpose kernels (tiny, once per launch)
// ---------------------------------------------------------------------------
__global__ __launch_bounds__(256)
void convert_w1(const float* __restrict__ W1, unsigned short* __restrict__ W1t)
{   // [L][272][128] f32 -> [L][128][288] bf16 (zero pad)
    const int o = blockIdx.x * 256 + threadIdx.x;
    const int l = o / (128 * K1P);
    const int r = o % (128 * K1P);
    const int n = r / K1P;
    const int k = r % K1P;
    const float v = (k < K1) ? W1[(size_t)l * K1 * H + (size_t)k * H + n] : 0.f;
    W1t[o] = f2bf(v);
}

__global__ __launch_bounds__(256)
void convert_w2(const float* __restrict__ W2, unsigned short* __restrict__ W2t)
{   // [L][128][128] -> transposed bf16
    const int o = blockIdx.x * 256 + threadIdx.x;
    const int l = o / (H * H);
    const int r = o % (H * H);
    const int n = r / H;
    const int k = r % H;
    W2t[o] = f2bf(W2[(size_t)l * H * H + (size_t)k * H + n]);
}

__global__ __launch_bounds__(256)
void convert_wu(const float* __restrict__ Wu, unsigned short* __restrict__ Wut)
{   // [L][256][128] -> [L][128][256] bf16
    const int o = blockIdx.x * 256 + threadIdx.x;
    const int l = o / (H * 256);
    const int r = o % (H * 256);
    const int n = r / 256;
    const int k = r % 256;
    Wut[o] = f2bf(Wu[(size_t)l * 256 * H + (size_t)k * H + n]);
}

__global__ __launch_bounds__(256)
void convert_wp(const float* __restrict__ Wp, unsigned short* __restrict__ Wpt)
{   // [128][128] -> transposed bf16
    const int o = blockIdx.x * 256 + threadIdx.x;
    const int n = o / H;
    const int k = o % H;
    Wpt[o] = f2bf(Wp[(size_t)k * H + n]);
}

// edge_attr -> bf16 in sorted order (once per launch; reused by all 3 layers)
__global__ __launch_bounds__(256)
void convert_ea(const float* __restrict__ ea, const int* __restrict__ perm,
                unsigned short* __restrict__ eabf)
{
    const int o = blockIdx.x * 256 + threadIdx.x;    // E*8 threads, 2 elems each
    const int p = o >> 3;
    const int j = (o & 7) * 2;
    const int pe = perm[p];
    const float2 v = *(const float2*)&ea[(size_t)pe * E_DIM + j];
    eabf[(size_t)p * E_DIM + j]     = f2bf(v.x);
    eabf[(size_t)p * E_DIM + j + 1] = f2bf(v.y);
}

// ---------------------------------------------------------------------------
// counting sort of edges by destination (i_idx)
// ---------------------------------------------------------------------------
__global__ __launch_bounds__(256)
void hist_kernel(const int* __restrict__ ei, int* __restrict__ hist)
{
    const int e = blockIdx.x * 256 + threadIdx.x;
    if (e < N_EDGES) atomicAdd(&hist[ei[e]], 1);
}

__global__ __launch_bounds__(256)
void scan_kernel(const int* __restrict__ hist, int* __restrict__ cursor)
{
    __shared__ int ps[256];
    const int t = threadIdx.x;
    const int CH = 196;                     // 256*196 = 50176 >= N
    const int base = t * CH;
    int s = 0;
    for (int i = 0; i < CH; ++i) { const int idx = base + i; if (idx < N_NODES) s += hist[idx]; }
    ps[t] = s; __syncthreads();
    for (int off = 1; off < 256; off <<= 1) {
        const int v = (t >= off) ? ps[t - off] : 0;
        __syncthreads();
        ps[t] += v;
        __syncthreads();
    }
    int run = (t > 0) ? ps[t - 1] : 0;
    for (int i = 0; i < CH; ++i) {
        const int idx = base + i;
        if (idx < N_NODES) { cursor[idx] = run; run += hist[idx]; }
    }
}

__global__ __launch_bounds__(256)
void scatter_kernel(const int* __restrict__ ei, int* __restrict__ cursor,
                    int* __restrict__ i_s, int* __restrict__ j_s, int* __restrict__ perm)
{
    const int e = blockIdx.x * 256 + threadIdx.x;
    if (e < N_EDGES) {
        const int d = ei[e];
        const int p = atomicAdd(&cursor[d], 1);
        i_s[p] = d;
        j_s[p] = ei[N_EDGES + e];
        perm[p] = e;
    }
}

// ---------------------------------------------------------------------------
// proj (MFMA): h = x @ Wp + b; emit fp32 h and bf16 mirror
// ---------------------------------------------------------------------------
__global__ __launch_bounds__(256)
void proj_mfma(const float* __restrict__ x, const unsigned short* __restrict__ Wpt,
               const float* __restrict__ b, float* __restrict__ h,
               unsigned short* __restrict__ hbf)
{
    __shared__ __align__(16) unsigned short A[MB][PS];
    const int tid = threadIdx.x;
    const int n0 = blockIdx.x * MB;
    const int wave = tid >> 6, lane = tid & 63, l15 = lane & 15, l4 = lane >> 4;
    const int colbase = wave * 32;

#pragma unroll
    for (int i = 0; i < 4; ++i) {
        const int f = tid + i * 256;
        const int row = f >> 5, c4 = f & 31;
        const int node = min(n0 + row, N_NODES - 1);
        const float4 v = *((const float4*)(x + (size_t)node * DIM_IN) + c4);
        unsigned short o[4] = { f2bf(v.x), f2bf(v.y), f2bf(v.z), f2bf(v.w) };
        *(uint2*)&A[row][c4 * 4] = *(const uint2*)o;
    }
    __syncthreads();

    f32x4 acc[2][2];
#pragma unroll
    for (int mt = 0; mt < 2; ++mt)
#pragma unroll
        for (int nt = 0; nt < 2; ++nt) acc[mt][nt] = (f32x4)0.f;

    for (int k = 0; k < DIM_IN; k += 32) {
        const s16x8 a0 = *(const s16x8*)&A[l15][k + l4 * 8];
        const s16x8 a1 = *(const s16x8*)&A[16 + l15][k + l4 * 8];
        const s16x8 b0 = *(const s16x8*)&Wpt[(size_t)(colbase + l15) * DIM_IN + k + l4 * 8];
        const s16x8 b1 = *(const s16x8*)&Wpt[(size_t)(colbase + 16 + l15) * DIM_IN + k + l4 * 8];
        acc[0][0] = __builtin_amdgcn_mfma_f32_16x16x32_bf16(a0, b0, acc[0][0], 0, 0, 0);
        acc[0][1] = __builtin_amdgcn_mfma_f32_16x16x32_bf16(a0, b1, acc[0][1], 0, 0, 0);
        acc[1][0] = __builtin_amdgcn_mfma_f32_16x16x32_bf16(a1, b0, acc[1][0], 0, 0, 0);
        acc[1][1] = __builtin_amdgcn_mfma_f32_16x16x32_bf16(a1, b1, acc[1][1], 0, 0, 0);
    }

    const float bi0 = b[colbase + l15], bi1 = b[colbase + 16 + l15];
#pragma unroll
    for (int mt = 0; mt < 2; ++mt)
#pragma unroll
        for (int r = 0; r < 4; ++r) {
            const int row = mt * 16 + l4 * 4 + r;
            const int n = n0 + row;
            if (n < N_NODES) {
                const float v0 = acc[mt][0][r] + bi0;
                const float v1 = acc[mt][1][r] + bi1;
                h[(size_t)n * H + colbase + l15]        = v0;
                h[(size_t)n * H + colbase + 16 + l15]   = v1;
                hbf[(size_t)n * H + colbase + l15]      = f2bf(v0);
                hbf[(size_t)n * H + colbase + 16 + l15] = f2bf(v1);
            }
        }
}

// ---------------------------------------------------------------------------
// edge message MLP: persistent blocks, software-pipelined gathers,
// weights in registers, LDS segment-reduce + atomics.
// ---------------------------------------------------------------------------
__global__ __launch_bounds__(256, 2)
void edge_kernel(const unsigned short* __restrict__ hbf,
                 const unsigned short* __restrict__ eabf,  // [E][16] bf16, sorted
                 const int*   __restrict__ i_s,
                 const int*   __restrict__ j_s,
                 const unsigned short* __restrict__ W1t,   // [128][288]
                 const float* __restrict__ b1,
                 const unsigned short* __restrict__ W2t,   // [128][128]
                 const float* __restrict__ b2,
                 float*       __restrict__ agg)
{
    __shared__ __align__(16) unsigned short A[MB][AS];          // 18944 B
    __shared__ __align__(16) float HFu[MB * FPS];               // 16896 B union
    __shared__ int idx_i_s[MB];
    unsigned short* Hid = (unsigned short*)HFu;                 // [32][HS]
    float* Afp = HFu;                                           // [32][FPS]

    const int tid  = threadIdx.x;
    const int wave = tid >> 6;
    const int lane = tid & 63;
    const int l15  = lane & 15;
    const int l4   = lane >> 4;
    const int colbase = wave * 32;

    // gather role: f = tid + i*256 -> e = (tid>>5)+i*8, c = tid&31
    const int ge_e = tid >> 5;
    const int ge_c = tid & 31;
    const int ge_ch = ge_c & 15;
    const int* __restrict__ gsel = (ge_c < 16) ? i_s : j_s;
    const int lds_off = (ge_c < 16 ? 0 : 128) + ge_ch * 8;

    // ---- weights into registers (per wave: its 32 output cols)
    s16x8 w1f[2][9], w2f[2][4];
#pragma unroll
    for (int kt = 0; kt < 9; ++kt) {
        w1f[0][kt] = *(const s16x8*)&W1t[(size_t)(colbase + l15) * K1P + kt * 32 + l4 * 8];
        w1f[1][kt] = *(const s16x8*)&W1t[(size_t)(colbase + 16 + l15) * K1P + kt * 32 + l4 * 8];
    }
#pragma unroll
    for (int kt = 0; kt < 4; ++kt) {
        w2f[0][kt] = *(const s16x8*)&W2t[(size_t)(colbase + l15) * H + kt * 32 + l4 * 8];
        w2f[1][kt] = *(const s16x8*)&W2t[(size_t)(colbase + 16 + l15) * H + kt * 32 + l4 * 8];
    }
    const float b1c0 = b1[colbase + l15], b1c1 = b1[colbase + 16 + l15];
    const float b2c0 = b2[colbase + l15], b2c1 = b2[colbase + 16 + l15];

    const int NT = N_EDGES / MB;
    int t = blockIdx.x;
    if (t >= NT) return;

    // ---- prologue: stage tile t
    {
        uint4 pf[4];
#pragma unroll
        for (int i = 0; i < 4; ++i) {
            const int e = ge_e + i * 8;
            const int node = gsel[t * MB + e];
            pf[i] = *((const uint4*)(hbf + (size_t)node * H) + ge_ch);
        }
#pragma unroll
        for (int i = 0; i < 4; ++i)
            *(uint4*)&A[ge_e + i * 8][lds_off] = pf[i];
        if (tid < 64) {
            const uint4 va = *((const uint4*)eabf + (size_t)t * 64 + tid);
            *(uint4*)&A[tid >> 1][256 + (tid & 1) * 8] = va;
        } else if (tid < 128) {
            const int tt = tid - 64;
            const uint4 z = {0, 0, 0, 0};
            *(uint4*)&A[tt >> 1][272 + (tt & 1) * 8] = z;   // stays zero all tiles
        }
        if (tid < MB) idx_i_s[tid] = i_s[t * MB + tid];
    }
    __syncthreads();

    for (; t < NT; t += gridDim.x) {
        const int t1 = t + gridDim.x;

        // ---- 1. issue prefetch for tile t1 (regs; latency hidden by GEMMs)
        uint4 pf[4];
        uint4 pfa = {0, 0, 0, 0};
        int   pfi = 0;
        if (t1 < NT) {
#pragma unroll
            for (int i = 0; i < 4; ++i) {
                const int e = ge_e + i * 8;
                const int node = gsel[t1 * MB + e];
                pf[i] = *((const uint4*)(hbf + (size_t)node * H) + ge_ch);
            }
            if (tid < 64) pfa = *((const uint4*)eabf + (size_t)t1 * 64 + tid);
            if (tid < MB) pfi = i_s[t1 * MB + tid];
        }

        // ---- 2. GEMM1: A[32x288] x W1 -> acc
        f32x4 acc[2][2];
#pragma unroll
        for (int mt = 0; mt < 2; ++mt)
#pragma unroll
            for (int nt = 0; nt < 2; ++nt) acc[mt][nt] = (f32x4)0.f;

#pragma unroll
        for (int kt = 0; kt < 9; ++kt) {
            const s16x8 a0 = *(const s16x8*)&A[l15][kt * 32 + l4 * 8];
            const s16x8 a1 = *(const s16x8*)&A[16 + l15][kt * 32 + l4 * 8];
            acc[0][0] = __builtin_amdgcn_mfma_f32_16x16x32_bf16(a0, w1f[0][kt], acc[0][0], 0, 0, 0);
            acc[0][1] = __builtin_amdgcn_mfma_f32_16x16x32_bf16(a0, w1f[1][kt], acc[0][1], 0, 0, 0);
            acc[1][0] = __builtin_amdgcn_mfma_f32_16x16x32_bf16(a1, w1f[0][kt], acc[1][0], 0, 0, 0);
            acc[1][1] = __builtin_amdgcn_mfma_f32_16x16x32_bf16(a1, w1f[1][kt], acc[1][1], 0, 0, 0);
        }
        __syncthreads();                 // A reads done (A free for prefetch write)

        // ---- 3. hid = relu(acc+b1) -> Hid
#pragma unroll
        for (int mt = 0; mt < 2; ++mt)
#pragma unroll
            for (int r = 0; r < 4; ++r) {
                const int row = mt * 16 + l4 * 4 + r;
                Hid[row * HS + colbase + l15]      = f2bf(fmaxf(acc[mt][0][r] + b1c0, 0.f));
                Hid[row * HS + colbase + 16 + l15] = f2bf(fmaxf(acc[mt][1][r] + b1c1, 0.f));
            }
        __syncthreads();

        // ---- 4. GEMM2: Hid[32x128] x W2 -> acc
#pragma unroll
        for (int mt = 0; mt < 2; ++mt)
#pragma unroll
            for (int nt = 0; nt < 2; ++nt) acc[mt][nt] = (f32x4)0.f;

#pragma unroll
        for (int kt = 0; kt < 4; ++kt) {
            const s16x8 a0 = *(const s16x8*)&Hid[l15 * HS + kt * 32 + l4 * 8];
            const s16x8 a1 = *(const s16x8*)&Hid[(16 + l15) * HS + kt * 32 + l4 * 8];
            acc[0][0] = __builtin_amdgcn_mfma_f32_16x16x32_bf16(a0, w2f[0][kt], acc[0][0], 0, 0, 0);
            acc[0][1] = __builtin_amdgcn_mfma_f32_16x16x32_bf16(a0, w2f[1][kt], acc[0][1], 0, 0, 0);
            acc[1][0] = __builtin_amdgcn_mfma_f32_16x16x32_bf16(a1, w2f[0][kt], acc[1][0], 0, 0, 0);
            acc[1][1] = __builtin_amdgcn_mfma_f32_16x16x32_bf16(a1, w2f[1][kt], acc[1][1], 0, 0, 0);
        }
        __syncthreads();                 // Hid reads done

        // ---- 5. m = relu(acc+b2) -> Afp (overlays Hid)
#pragma unroll
        for (int mt = 0; mt < 2; ++mt)
#pragma unroll
            for (int r = 0; r < 4; ++r) {
                const int row = mt * 16 + l4 * 4 + r;
                Afp[row * FPS + colbase + l15]      = fmaxf(acc[mt][0][r] + b2c0, 0.f);
                Afp[row * FPS + colbase + 16 + l15] = fmaxf(acc[mt][1][r] + b2c1, 0.f);
            }
        __syncthreads();

        // ---- 6. segment reduce over sorted dests (~1 atomic/segment/col)
        {
            const int c    = tid & 127;
            const int half = tid >> 7;
            int cur = idx_i_s[half * 16];
            float s = 0.f;
            for (int r = half * 16; r < half * 16 + 16; ++r) {
                const int d = idx_i_s[r];
                if (d != cur) {
                    atomicAdd(&agg[(size_t)cur * H + c], s);
                    s = 0.f; cur = d;
                }
                s += Afp[r * FPS + c];
            }
            atomicAdd(&agg[(size_t)cur * H + c], s);
        }
        __syncthreads();                 // Afp/idx reads done

        // ---- 7. drain prefetch into LDS for next tile
        if (t1 < NT) {
#pragma unroll
            for (int i = 0; i < 4; ++i)
                *(uint4*)&A[ge_e + i * 8][lds_off] = pf[i];
            if (tid < 64)
                *(uint4*)&A[tid >> 1][256 + (tid & 1) * 8] = pfa;
            if (tid < MB) idx_i_s[tid] = pfi;
        }
        __syncthreads();
    }
}

// ---------------------------------------------------------------------------
// node update (MFMA): out = relu([h,agg]Wu+b); h = LN(out+h); bf16 mirror
// ---------------------------------------------------------------------------
__global__ __launch_bounds__(256)
void update_mfma(float* __restrict__ h, const float* __restrict__ agg,
                 const unsigned short* __restrict__ Wut, const float* __restrict__ b,
                 const float* __restrict__ g, const float* __restrict__ bln,
                 unsigned short* __restrict__ hbf)
{
    __shared__ __align__(16) unsigned short A[MB][US];
    float* Afp = (float*)&A[0][0];

    const int tid = threadIdx.x;
    const int n0 = blockIdx.x * MB;
    const int wave = tid >> 6, lane = tid & 63, l15 = lane & 15, l4 = lane >> 4;
    const int colbase = wave * 32;

#pragma unroll
    for (int i = 0; i < 2; ++i) {
        const int f = tid + i * 256;
        const int row = f >> 4, c = f & 15;
        const int node = min(n0 + row, N_NODES - 1);
        const uint4 v = *((const uint4*)(hbf + (size_t)node * H) + c);
        *(uint4*)&A[row][c * 8] = v;
    }
#pragma unroll
    for (int i = 0; i < 4; ++i) {
        const int f = tid + i * 256;
        const int row = f >> 5, c4 = f & 31;
        const int node = min(n0 + row, N_NODES - 1);
        const float4 v = *((const float4*)(agg + (size_t)node * H) + c4);
        unsigned short o[4] = { f2bf(v.x), f2bf(v.y), f2bf(v.z), f2bf(v.w) };
        *(uint2*)&A[row][128 + c4 * 4] = *(const uint2*)o;
    }
    __syncthreads();

    f32x4 acc[2][2];
#pragma unroll
    for (int mt = 0; mt < 2; ++mt)
#pragma unroll
        for (int nt = 0; nt < 2; ++nt) acc[mt][nt] = (f32x4)0.f;

    for (int k = 0; k < 256; k += 32) {
        const s16x8 a0 = *(const s16x8*)&A[l15][k + l4 * 8];
        const s16x8 a1 = *(const s16x8*)&A[16 + l15][k + l4 * 8];
        const s16x8 b0 = *(const s16x8*)&Wut[(size_t)(colbase + l15) * 256 + k + l4 * 8];
        const s16x8 b1 = *(const s16x8*)&Wut[(size_t)(colbase + 16 + l15) * 256 + k + l4 * 8];
        acc[0][0] = __builtin_amdgcn_mfma_f32_16x16x32_bf16(a0, b0, acc[0][0], 0, 0, 0);
        acc[0][1] = __builtin_amdgcn_mfma_f32_16x16x32_bf16(a0, b1, acc[0][1], 0, 0, 0);
        acc[1][0] = __builtin_amdgcn_mfma_f32_16x16x32_bf16(a1, b0, acc[1][0], 0, 0, 0);
        acc[1][1] = __builtin_amdgcn_mfma_f32_16x16x32_bf16(a1, b1, acc[1][1], 0, 0, 0);
    }
    __syncthreads();

    {
        const float bi0 = b[colbase + l15], bi1 = b[colbase + 16 + l15];
#pragma unroll
        for (int mt = 0; mt < 2; ++mt)
#pragma unroll
            for (int r = 0; r < 4; ++r) {
                const int row = mt * 16 + l4 * 4 + r;
                Afp[row * FPS + colbase + l15]      = fmaxf(acc[mt][0][r] + bi0, 0.f);
                Afp[row * FPS + colbase + 16 + l15] = fmaxf(acc[mt][1][r] + bi1, 0.f);
            }
    }
    __syncthreads();

    const float g0 = g[lane],   g1 = g[64 + lane];
    const float l0 = bln[lane], l1 = bln[64 + lane];
    for (int q = 0; q < 8; ++q) {
        const int row = wave * 8 + q;
        const int n = n0 + row;
        if (n >= N_NODES) break;
        const float hr0 = h[(size_t)n * H + lane];
        const float hr1 = h[(size_t)n * H + 64 + lane];
        float v0 = Afp[row * FPS + lane]      + hr0;
        float v1 = Afp[row * FPS + 64 + lane] + hr1;
        float s = v0 + v1;
#pragma unroll
        for (int off = 32; off > 0; off >>= 1) s += __shfl_xor(s, off, 64);
        const float mu = s * (1.f / 128.f);
        const float d0 = v0 - mu, d1 = v1 - mu;
        float vs = d0 * d0 + d1 * d1;
#pragma unroll
        for (int off = 32; off > 0; off >>= 1) vs += __shfl_xor(vs, off, 64);
        const float inv = rsqrtf(vs * (1.f / 128.f) + 1e-5f);
        const float o0 = d0 * inv * g0 + l0;
        const float o1 = d1 * inv * g1 + l1;
        h[(size_t)n * H + lane]        = o0;
        h[(size_t)n * H + 64 + lane]   = o1;
        hbf[(size_t)n * H + lane]      = f2bf(o0);
        hbf[(size_t)n * H + 64 + lane] = f2bf(o1);
    }
}

// ---------------------------------------------------------------------------
__global__ __launch_bounds__(64)
void final_kernel(const float* __restrict__ h,
                  const float* __restrict__ g, const float* __restrict__ b,
                  float* __restrict__ out)
{
    const int t = threadIdx.x;
    const float g0 = g[t], g1 = g[64 + t];
    const float b0 = b[t], b1 = b[64 + t];
    float a0 = 0.f, a1 = 0.f;

    for (int n = blockIdx.x; n < N_NODES; n += gridDim.x) {
        const float v0 = h[(size_t)n * H + t];
        const float v1 = h[(size_t)n * H + 64 + t];
        float s = v0 + v1;
#pragma unroll
        for (int off = 32; off > 0; off >>= 1) s += __shfl_xor(s, off, 64);
        const float mu = s * (1.f / 128.f);
        const float d0 = v0 - mu, d1 = v1 - mu;
        float vs = d0 * d0 + d1 * d1;
#pragma unroll
        for (int off = 32; off > 0; off >>= 1) vs += __shfl_xor(vs, off, 64);
        const float inv = rsqrtf(vs * (1.f / 128.f) + 1e-5f);
        a0 += d0 * inv * g0 + b0;
        a1 += d1 * inv * g1 + b1;
    }
    atomicAdd(&out[t],      a0 * (1.f / N_NODES));
    atomicAdd(&out[64 + t], a1 * (1.f / N_NODES));
}

// ---------------------------------------------------------------------------
extern "C" void kernel_launch(void* const* d_in, const int* in_sizes, int n_in,
                              void* d_out, int out_size, void* d_ws, size_t ws_size,
                              hipStream_t stream)
{
    const float* x         = (const float*)d_in[0];
    const float* edge_attr = (const float*)d_in[1];
    const int*   edge_idx  = (const int*)  d_in[2];
    const float* proj_W    = (const float*)d_in[3];
    const float* proj_b    = (const float*)d_in[4];
    const float* msg_W1    = (const float*)d_in[5];
    const float* msg_b1    = (const float*)d_in[6];
    const float* msg_W2    = (const float*)d_in[7];
    const float* msg_b2    = (const float*)d_in[8];
    const float* upd_W     = (const float*)d_in[9];
    const float* upd_b     = (const float*)d_in[10];
    const float* ln_g      = (const float*)d_in[11];
    const float* ln_b      = (const float*)d_in[12];
    const float* out_g     = (const float*)d_in[13];
    const float* out_b     = (const float*)d_in[14];
    float* out = (float*)d_out;

    char* w = (char*)d_ws;
    float* h   = (float*)w;                   w += (size_t)N_NODES * H * 4;
    float* agg = (float*)w;                   w += (size_t)N_NODES * H * 4;
    unsigned short* hbf  = (unsigned short*)w; w += (size_t)N_NODES * H * 2;
    unsigned short* eabf = (unsigned short*)w; w += (size_t)N_EDGES * E_DIM * 2;
    unsigned short* W1t  = (unsigned short*)w; w += (size_t)NLAYERS * H * K1P * 2;
    unsigned short* W2t  = (unsigned short*)w; w += (size_t)NLAYERS * H * H * 2;
    unsigned short* Wut  = (unsigned short*)w; w += (size_t)NLAYERS * H * 256 * 2;
    unsigned short* Wpt  = (unsigned short*)w; w += (size_t)H * DIM_IN * 2;
    int* hist   = (int*)w;                    w += (size_t)N_NODES * 4;
    int* cursor = (int*)w;                    w += (size_t)N_NODES * 4;
    int* i_s    = (int*)w;                    w += (size_t)N_EDGES * 4;
    int* j_s    = (int*)w;                    w += (size_t)N_EDGES * 4;
    int* perm   = (int*)w;                    w += (size_t)N_EDGES * 4;

    convert_w1<<<(NLAYERS * H * K1P) / 256, 256, 0, stream>>>(msg_W1, W1t);
    convert_w2<<<(NLAYERS * H * H) / 256, 256, 0, stream>>>(msg_W2, W2t);
    convert_wu<<<(NLAYERS * H * 256) / 256, 256, 0, stream>>>(upd_W, Wut);
    convert_wp<<<(H * DIM_IN) / 256, 256, 0, stream>>>(proj_W, Wpt);

    hipMemsetAsync(hist, 0, (size_t)N_NODES * 4, stream);
    hist_kernel<<<(N_EDGES + 255) / 256, 256, 0, stream>>>(edge_idx, hist);
    scan_kernel<<<1, 256, 0, stream>>>(hist, cursor);
    scatter_kernel<<<(N_EDGES + 255) / 256, 256, 0, stream>>>(edge_idx, cursor, i_s, j_s, perm);
    convert_ea<<<(N_EDGES * 8) / 256, 256, 0, stream>>>(edge_attr, perm, eabf);

    const int nblk = (N_NODES + MB - 1) / MB;
    proj_mfma<<<nblk, 256, 0, stream>>>(x, Wpt, proj_b, h, hbf);

    for (int l = 0; l < NLAYERS; ++l) {
        hipMemsetAsync(agg, 0, (size_t)N_NODES * H * sizeof(float), stream);
        edge_kernel<<<1024, 256, 0, stream>>>(
            hbf, eabf, i_s, j_s,
            W1t + (size_t)l * H * K1P, msg_b1 + (size_t)l * H,
            W2t + (size_t)l * H * H,   msg_b2 + (size_t)l * H, agg);
        update_mfma<<<nblk, 256, 0, stream>>>(
            h, agg, Wut + (size_t)l * H * 256, upd_b + (size_t)l * H,
            ln_g + (size_t)l * H, ln_b + (size_t)l * H, hbf);
    }

    hipMemsetAsync(out, 0, H * sizeof(float), stream);
    final_kernel<<<512, 64, 0, stream>>>(h, out_g, out_b, out);
}